// Round 9
// baseline (231.520 us; speedup 1.0000x reference)
//
#include <hip/hip_runtime.h>
#include <math.h>

typedef __bf16 bf16_t;
typedef __bf16 bf16x4_v __attribute__((ext_vector_type(4)));
typedef __bf16 bf16x8_t __attribute__((ext_vector_type(8)));
typedef float f32x4_t __attribute__((ext_vector_type(4)));
typedef unsigned uint2_t __attribute__((ext_vector_type(2)));
typedef unsigned uint4_t __attribute__((ext_vector_type(4)));

#define S_LEN 4096
#define DM 512
#define NH 8
#define DH 64
#define MTOT 8192  // B*S

// 1/sqrt(64) * log2(e): scores come out in log2 domain -> exp2 directly
#define Q_SCALE 0.1803368801111204f

#define REG 4194304  // 8192*512 elements per [B,H,S,DH] region

__device__ inline f32x4_t mfma16(bf16x8_t a, bf16x8_t b, f32x4_t c) {
    return __builtin_amdgcn_mfma_f32_16x16x32_bf16(a, b, c, 0, 0, 0);
}

__device__ inline unsigned pkbf16(float a, float b) {
    unsigned short ra = __builtin_bit_cast(unsigned short, (bf16_t)a);
    unsigned short rb = __builtin_bit_cast(unsigned short, (bf16_t)b);
    return (unsigned)ra | ((unsigned)rb << 16);
}

__device__ inline bf16x8_t cvt8(float4 a, float4 b) {
    bf16x8_t h;
    h[0] = (bf16_t)a.x; h[1] = (bf16_t)a.y; h[2] = (bf16_t)a.z; h[3] = (bf16_t)a.w;
    h[4] = (bf16_t)b.x; h[5] = (bf16_t)b.y; h[6] = (bf16_t)b.z; h[7] = (bf16_t)b.w;
    return h;
}

__device__ inline void async_copy16(const void* g, void* l) {
    __builtin_amdgcn_global_load_lds(
        (const __attribute__((address_space(1))) void*)g,
        (__attribute__((address_space(3))) void*)l, 16, 0, 0);
}

// ---------------------------------------------------------------------------
// GEMM 1 (fp32 in, bf16 out; conversion fused into staging): P_p = X_p@W_p^T+b
// A (X, HBM-bound) register-prefetched across the compute phase; B (W) is
// L2-resident and loaded in the write phase. XOR-chunk-swizzled bf16 LDS.
// Grid (n=4, m=64, p=3): n fastest -> consecutive blocks share the X-tile (L2).
// p<2: operand-swapped MFMA -> bf16x4 epilogue; p=2: V^T output.
// ---------------------------------------------------------------------------
__global__ __launch_bounds__(256) void gemm_qkv(
    const float* __restrict__ X0, const float* __restrict__ X1, const float* __restrict__ X2,
    const float* __restrict__ W0, const float* __restrict__ W1, const float* __restrict__ W2,
    const float* __restrict__ B0, const float* __restrict__ B1, const float* __restrict__ B2,
    bf16_t* __restrict__ dst_base)
{
    const int p = blockIdx.z;
    const float* __restrict__ X  = (p == 0) ? X0 : ((p == 1) ? X1 : X2);
    const float* __restrict__ W  = (p == 0) ? W0 : ((p == 1) ? W1 : W2);
    const float* __restrict__ Bi = (p == 0) ? B0 : ((p == 1) ? B1 : B2);
    bf16_t* __restrict__ dst = dst_base + (size_t)p * REG;

    const int n0 = blockIdx.x * 128;
    const int m0 = blockIdx.y * 128;
    const int tid = threadIdx.x;
    const int lane = tid & 63, wid = tid >> 6;
    const int lm = lane & 15, lg = lane >> 4;
    const int wm = (wid >> 1) * 64, wn = (wid & 1) * 64;

    __shared__ __align__(16) bf16_t As[128 * 64];  // 16B chunks XOR ^(row&7)
    __shared__ __align__(16) bf16_t Bs[128 * 64];

    f32x4_t acc[4][4] = {};

    const int r0 = tid >> 3, c7 = tid & 7;
    const int cA0 = ((lg) ^ (lm & 7)) * 8;
    const int cA1 = ((4 + lg) ^ (lm & 7)) * 8;

    int rows[4], chs[4];
#pragma unroll
    for (int i = 0; i < 4; ++i) { rows[i] = i * 32 + r0; chs[i] = c7 ^ (rows[i] & 7); }

    // prologue: prefetch A tile kb=0 (fp32)
    float4 pa0[4], pa1[4];
#pragma unroll
    for (int i = 0; i < 4; ++i) {
        const float* s = X + (size_t)(m0 + rows[i]) * DM + chs[i] * 8;
        pa0[i] = *(const float4*)s; pa1[i] = *(const float4*)(s + 4);
    }

    for (int kb = 0; kb < DM / 64; ++kb) {
        // B loads (W is L2-hot after the first m-block)
        float4 pb0[4], pb1[4];
#pragma unroll
        for (int i = 0; i < 4; ++i) {
            const float* s = W + (size_t)(n0 + rows[i]) * DM + kb * 64 + chs[i] * 8;
            pb0[i] = *(const float4*)s; pb1[i] = *(const float4*)(s + 4);
        }
        __syncthreads();  // previous compute done reading LDS
#pragma unroll
        for (int i = 0; i < 4; ++i) {
            *(bf16x8_t*)((char*)As + (i * 256 + tid) * 16) = cvt8(pa0[i], pa1[i]);
            *(bf16x8_t*)((char*)Bs + (i * 256 + tid) * 16) = cvt8(pb0[i], pb1[i]);
        }
        __syncthreads();  // writes visible
        if (kb < DM / 64 - 1) {  // prefetch A kb+1; latency hides behind compute
            const int k1 = (kb + 1) * 64;
#pragma unroll
            for (int i = 0; i < 4; ++i) {
                const float* s = X + (size_t)(m0 + rows[i]) * DM + k1 + chs[i] * 8;
                pa0[i] = *(const float4*)s; pa1[i] = *(const float4*)(s + 4);
            }
        }
#pragma unroll
        for (int kd = 0; kd < 2; ++kd) {
            const int co = kd ? cA1 : cA0;
            bf16x8_t fa[4], fb[4];
#pragma unroll
            for (int mt = 0; mt < 4; ++mt) {
                fa[mt] = *(const bf16x8_t*)(As + (wm + mt * 16 + lm) * 64 + co);
                fb[mt] = *(const bf16x8_t*)(Bs + (wn + mt * 16 + lm) * 64 + co);
            }
            if (p < 2) {
#pragma unroll
                for (int mt = 0; mt < 4; ++mt)
#pragma unroll
                    for (int nt = 0; nt < 4; ++nt)
                        acc[nt][mt] = mfma16(fb[nt], fa[mt], acc[nt][mt]);  // D[dc][s]
            } else {
#pragma unroll
                for (int mt = 0; mt < 4; ++mt)
#pragma unroll
                    for (int nt = 0; nt < 4; ++nt)
                        acc[mt][nt] = mfma16(fa[mt], fb[nt], acc[mt][nt]);  // D[s][dc]
            }
        }
    }

    if (p == 2) {
        // V transposed: dst[(bh*DH + dc)*S_LEN + s], 8B stores (4 consecutive s)
#pragma unroll
        for (int nt = 0; nt < 4; ++nt) {
            int col = n0 + wn + nt * 16 + lm;
            float bv = Bi[col];
            int h = (col >> 6) & 7, dc = col & 63;
#pragma unroll
            for (int mt = 0; mt < 4; ++mt) {
                int mrow = m0 + wm + mt * 16 + lg * 4;
                int bb = mrow >> 12, s = mrow & (S_LEN - 1);
                bf16x4_v pk;
#pragma unroll
                for (int r = 0; r < 4; ++r) pk[r] = (bf16_t)(acc[mt][nt][r] + bv);
                *(bf16x4_v*)&dst[(((size_t)(bb * NH + h)) * DH + dc) * S_LEN + s] = pk;
            }
        }
    } else {
        const float scale = (p == 0) ? Q_SCALE : 1.0f;
#pragma unroll
        for (int nt = 0; nt < 4; ++nt) {
            int ncol = n0 + wn + nt * 16 + lg * 4;
            float4 bv4 = *(const float4*)&Bi[ncol];
            int h = (ncol >> 6) & 7, dc = ncol & 63;
#pragma unroll
            for (int mt = 0; mt < 4; ++mt) {
                int m = m0 + wm + mt * 16 + lm;
                int bb = m >> 12, s = m & (S_LEN - 1);
                bf16x4_v pk;
                pk[0] = (bf16_t)((acc[nt][mt][0] + bv4.x) * scale);
                pk[1] = (bf16_t)((acc[nt][mt][1] + bv4.y) * scale);
                pk[2] = (bf16_t)((acc[nt][mt][2] + bv4.z) * scale);
                pk[3] = (bf16_t)((acc[nt][mt][3] + bv4.w) * scale);
                *(bf16x4_v*)&dst[(((size_t)(bb * NH + h)) * S_LEN + s) * DH + dc] = pk;
            }
        }
    }
}

// ---------------------------------------------------------------------------
// Flash attention v6: v5 (dbuf, K=32 PV) + l via ones-MFMA. l = ones . P^T
// accumulated with the already-built bP frags (4 extra MFMA/iter) — removes
// 32 VALU adds/iter and the entire epilogue shuffle-reduce: every lane's
// acc_l[nt][0] IS the half-sum for q = lane&15.
// ---------------------------------------------------------------------------
__global__ __launch_bounds__(512, 4) void flash_attn(
    const bf16_t* __restrict__ Qh, const bf16_t* __restrict__ Kh,
    const bf16_t* __restrict__ Vth, bf16_t* __restrict__ O)
{
    const int bh = blockIdx.y;  // b*8 + h
    const int q0 = blockIdx.x * 128;
    const int tid = threadIdx.x;
    const int lane = tid & 63, wid = tid >> 6;
    const int lm = lane & 15, lg = lane >> 4;
    const int qg = wid & 3;    // q-group: 32 q rows
    const int kvh = wid >> 2;  // kv half

    const bf16_t* __restrict__ Qb  = Qh  + (size_t)bh * S_LEN * DH;
    const bf16_t* __restrict__ Kb  = Kh  + (size_t)bh * S_LEN * DH;
    const bf16_t* __restrict__ Vtg = Vth + (size_t)bh * S_LEN * DH;  // [d][s]

    __shared__ __align__(16) char smem[65536];

    bf16x8_t bQ[2][2];
#pragma unroll
    for (int nt = 0; nt < 2; ++nt)
#pragma unroll
        for (int kd = 0; kd < 2; ++kd)
            bQ[nt][kd] = *(const bf16x8_t*)(Qb + (size_t)(q0 + qg * 32 + nt * 16 + lm) * DH + kd * 32 + lg * 8);

    bf16x8_t onesA;
#pragma unroll
    for (int i = 0; i < 8; ++i) onesA[i] = (bf16_t)1.0f;

    f32x4_t o_acc[4][2] = {};
    f32x4_t acc_l[2] = {};   // ones . P^T : every component = half l per q=lm

    const int srow = tid >> 3;
    const int slch = (tid & 7) ^ (srow & 7);
    const bf16_t* gK = Kb + (size_t)srow * DH + slch * 8;
    const bf16_t* gV = Vtg + (size_t)srow * S_LEN + slch * 8;

    const int cK0 = ((lg) ^ (lm & 7)) * 16;
    const int cK1 = ((4 + lg) ^ (lm & 7)) * 16;

    // prologue: stage tile 0 into buffer 0
    {
        char* b = smem;
        async_copy16(gK, b + tid * 16);
        async_copy16(gK + (size_t)64 * DH, b + 8192 + tid * 16);
        async_copy16(gV, b + 16384 + tid * 16);
        async_copy16(gV + 64, b + 24576 + tid * 16);
    }

    const int NT = S_LEN / 128;
    for (int it = 0; it < NT; ++it) {
        const char* buf = smem + (it & 1) * 32768;
        __syncthreads();  // drains this buffer's loads (vmcnt 0) + all waves

        if (it + 1 < NT) {
            char* nb = smem + ((it + 1) & 1) * 32768;
            const int kvb = (it + 1) * 128;
            async_copy16(gK + (size_t)kvb * DH, nb + tid * 16);
            async_copy16(gK + (size_t)(kvb + 64) * DH, nb + 8192 + tid * 16);
            async_copy16(gV + kvb, nb + 16384 + tid * 16);
            async_copy16(gV + kvb + 64, nb + 24576 + tid * 16);
        }

        const char* ksb = buf + kvh * 8192;
        const char* vsb = buf + 16384 + kvh * 8192;

        // --- QK + exp2 + pack (per kv16 tile mt) ---
        unsigned pk[4][2][2];  // [kv16 tile][q tile][dword]
#pragma unroll
        for (int mt = 0; mt < 4; ++mt) {
            const char* krow = ksb + (mt * 16 + lm) * 128;
            bf16x8_t aK0 = *(const bf16x8_t*)(krow + cK0);
            bf16x8_t aK1 = *(const bf16x8_t*)(krow + cK1);
            f32x4_t s0 = {}, s1 = {};
            s0 = mfma16(aK0, bQ[0][0], s0);
            s0 = mfma16(aK1, bQ[0][1], s0);
            s1 = mfma16(aK0, bQ[1][0], s1);
            s1 = mfma16(aK1, bQ[1][1], s1);
            pk[mt][0][0] = pkbf16(__builtin_amdgcn_exp2f(s0[0]), __builtin_amdgcn_exp2f(s0[1]));
            pk[mt][0][1] = pkbf16(__builtin_amdgcn_exp2f(s0[2]), __builtin_amdgcn_exp2f(s0[3]));
            pk[mt][1][0] = pkbf16(__builtin_amdgcn_exp2f(s1[0]), __builtin_amdgcn_exp2f(s1[1]));
            pk[mt][1][1] = pkbf16(__builtin_amdgcn_exp2f(s1[2]), __builtin_amdgcn_exp2f(s1[3]));
        }

        // --- PV: O^T[d][q] += V^T . P^T (K=32 pi-permuted); l += ones . P^T ---
#pragma unroll
        for (int cc = 0; cc < 2; ++cc) {
            const int ca = 2 * cc, cb = 2 * cc + 1;
            bf16x8_t bP0 = __builtin_bit_cast(bf16x8_t, (uint4_t){pk[ca][0][0], pk[ca][0][1], pk[cb][0][0], pk[cb][0][1]});
            bf16x8_t bP1 = __builtin_bit_cast(bf16x8_t, (uint4_t){pk[ca][1][0], pk[ca][1][1], pk[cb][1][0], pk[cb][1][1]});
            acc_l[0] = mfma16(onesA, bP0, acc_l[0]);
            acc_l[1] = mfma16(onesA, bP1, acc_l[1]);
            const int pc0 = (ca * 2 + (lg >> 1)) ^ (lm & 7);
            const int pc1 = (cb * 2 + (lg >> 1)) ^ (lm & 7);
#pragma unroll
            for (int mt = 0; mt < 4; ++mt) {
                const char* vrow = vsb + (mt * 16 + lm) * 128;
                uint2_t va0 = *(const uint2_t*)(vrow + pc0 * 16 + (lg & 1) * 8);
                uint2_t va1 = *(const uint2_t*)(vrow + pc1 * 16 + (lg & 1) * 8);
                bf16x8_t vA = __builtin_bit_cast(bf16x8_t, (uint4_t){va0[0], va0[1], va1[0], va1[1]});
                o_acc[mt][0] = mfma16(vA, bP0, o_acc[mt][0]);
                o_acc[mt][1] = mfma16(vA, bP1, o_acc[mt][1]);
            }
        }
    }

    __syncthreads();  // all compute done before smem is reused for the merge

    float* ob = (float*)smem + qg * (32 * 66);
    float* lb = (float*)(smem + 33792);

    if (kvh == 1) {
#pragma unroll
        for (int nt = 0; nt < 2; ++nt) {
#pragma unroll
            for (int mt = 0; mt < 4; ++mt)
#pragma unroll
                for (int r = 0; r < 4; ++r)
                    ob[(nt * 16 + lm) * 66 + mt * 16 + lg * 4 + r] = o_acc[mt][nt][r];
            if (lg == 0) lb[qg * 32 + nt * 16 + lm] = acc_l[nt][0];
        }
    }
    __syncthreads();
    if (kvh == 0) {
        const int bb = bh >> 3, h = bh & 7;
#pragma unroll
        for (int nt = 0; nt < 2; ++nt) {
            float ltot = acc_l[nt][0] + lb[qg * 32 + nt * 16 + lm];
            float inv = 1.0f / ltot;
            int q = q0 + qg * 32 + nt * 16 + lm;
            size_t base = ((size_t)(bb * S_LEN + q)) * DM + h * DH;
#pragma unroll
            for (int mt = 0; mt < 4; ++mt) {
                const float* orow = &ob[(nt * 16 + lm) * 66 + mt * 16 + lg * 4];
                bf16x4_v pkd;
#pragma unroll
                for (int r = 0; r < 4; ++r)
                    pkd[r] = (bf16_t)((o_acc[mt][nt][r] + orow[r]) * inv);
                *(bf16x4_v*)&O[base + mt * 16 + lg * 4] = pkd;
            }
        }
    }
}

// ---------------------------------------------------------------------------
// GEMM 2: out = O @ Wo^T + bo (fp32 out). A (bf16) via global_load_lds;
// Wo read fp32 and converted in staging. 64x128 tile, swapped MFMA, float4
// stores. Grid (n=4, m=128): consecutive blocks share the A-tile (L2).
// ---------------------------------------------------------------------------
__global__ __launch_bounds__(256) void gemm_out(
    const bf16_t* __restrict__ A, const float* __restrict__ W,
    const float* __restrict__ Bi, float* __restrict__ out)
{
    const int n0 = blockIdx.x * 128;
    const int m0 = blockIdx.y * 64;
    const int tid = threadIdx.x;
    const int lane = tid & 63, wid = tid >> 6;
    const int lm = lane & 15, lg = lane >> 4;
    const int wm = (wid >> 1) * 32, wn = (wid & 1) * 64;

    __shared__ __align__(16) bf16_t As[64 * 64];
    __shared__ __align__(16) bf16_t Bs[128 * 64];

    f32x4_t acc[4][2] = {};  // [n-tile][m-tile], swapped: D[n][m]

    const int r0 = tid >> 3, c7 = tid & 7;
    const int cA0 = ((lg) ^ (lm & 7)) * 8;
    const int cA1 = ((4 + lg) ^ (lm & 7)) * 8;

    int arow[2], ach[2], brow[4], bch[4];
#pragma unroll
    for (int i = 0; i < 2; ++i) {
        int idx = i * 256 + tid;
        arow[i] = idx >> 3; ach[i] = (idx & 7) ^ (arow[i] & 7);
    }
#pragma unroll
    for (int i = 0; i < 4; ++i) { brow[i] = i * 32 + r0; bch[i] = c7 ^ (brow[i] & 7); }

    for (int kb = 0; kb < DM / 64; ++kb) {
        const int k0 = kb * 64;
        // B (Wo, L2-hot) fp32 loads into regs
        float4 pb0[4], pb1[4];
#pragma unroll
        for (int i = 0; i < 4; ++i) {
            const float* s = W + (size_t)(n0 + brow[i]) * DM + k0 + bch[i] * 8;
            pb0[i] = *(const float4*)s; pb1[i] = *(const float4*)(s + 4);
        }
        __syncthreads();  // previous compute done reading LDS
#pragma unroll
        for (int i = 0; i < 2; ++i)
            async_copy16(A + (size_t)(m0 + arow[i]) * DM + k0 + ach[i] * 8,
                         (char*)As + (i * 256 + tid) * 16);
#pragma unroll
        for (int i = 0; i < 4; ++i)
            *(bf16x8_t*)((char*)Bs + (i * 256 + tid) * 16) = cvt8(pb0[i], pb1[i]);
        __syncthreads();  // drains async A (vmcnt 0) + B writes visible
#pragma unroll
        for (int kd = 0; kd < 2; ++kd) {
            const int co = kd ? cA1 : cA0;
            bf16x8_t fa[2], fb[4];
#pragma unroll
            for (int mt = 0; mt < 2; ++mt)
                fa[mt] = *(const bf16x8_t*)(As + (wm + mt * 16 + lm) * 64 + co);
#pragma unroll
            for (int nt = 0; nt < 4; ++nt)
                fb[nt] = *(const bf16x8_t*)(Bs + (wn + nt * 16 + lm) * 64 + co);
#pragma unroll
            for (int nt = 0; nt < 4; ++nt)
#pragma unroll
                for (int mt = 0; mt < 2; ++mt)
                    acc[nt][mt] = mfma16(fb[nt], fa[mt], acc[nt][mt]);
        }
    }

#pragma unroll
    for (int nt = 0; nt < 4; ++nt) {
        int ncol = n0 + wn + nt * 16 + lg * 4;
        float4 bv4 = *(const float4*)&Bi[ncol];
#pragma unroll
        for (int mt = 0; mt < 2; ++mt) {
            int m = m0 + wm + mt * 16 + lm;
            float4 ov;
            ov.x = acc[nt][mt][0] + bv4.x;
            ov.y = acc[nt][mt][1] + bv4.y;
            ov.z = acc[nt][mt][2] + bv4.z;
            ov.w = acc[nt][mt][3] + bv4.w;
            *(float4*)&out[(size_t)m * DM + ncol] = ov;
        }
    }
}

// ---------------------------------------------------------------------------
extern "C" void kernel_launch(void* const* d_in, const int* in_sizes, int n_in,
                              void* d_out, int out_size, void* d_ws, size_t ws_size,
                              hipStream_t stream)
{
    const float* q  = (const float*)d_in[0];
    const float* k  = (const float*)d_in[1];
    const float* v  = (const float*)d_in[2];
    const float* wq = (const float*)d_in[3];
    const float* bq = (const float*)d_in[4];
    const float* wk = (const float*)d_in[5];
    const float* bk = (const float*)d_in[6];
    const float* wv = (const float*)d_in[7];
    const float* bv = (const float*)d_in[8];
    const float* wo = (const float*)d_in[9];
    const float* bo = (const float*)d_in[10];
    float* out = (float*)d_out;

    // ws layout (bf16 elements): Ob | Qh | Kh | VTh (4 x REG = 33.5 MB)
    bf16_t* ws  = (bf16_t*)d_ws;
    bf16_t* Ob  = ws;
    bf16_t* Qh  = ws + REG;
    bf16_t* Kh  = ws + 2 * (size_t)REG;
    bf16_t* VTh = ws + 3 * (size_t)REG;

    dim3 g1(DM / 128, MTOT / 128, 3);   // n fastest for X-tile L2 reuse
    gemm_qkv<<<g1, 256, 0, stream>>>(q, k, v, wq, wk, wv, bq, bk, bv, Qh);

    dim3 g2(S_LEN / 128, 2 * NH, 1);
    flash_attn<<<g2, 512, 0, stream>>>(Qh, Kh, VTh, Ob);

    dim3 g3(DM / 128, MTOT / 64, 1);    // n fastest for O-tile L2 reuse
    gemm_out<<<g3, 256, 0, stream>>>(Ob, wo, bo, out);
}